// Round 1
// baseline (3185.539 us; speedup 1.0000x reference)
//
#include <hip/hip_runtime.h>
#include <math.h>

#define CDIM 256
#define HD 8
#define DD 32
#define TM 64
#define TN 64
#define BK 16

// ---------------- bucket building ----------------
__global__ void count_ntype_k(const int* __restrict__ ntype, int N, int* __restrict__ cnt) {
    int i = blockIdx.x * 256 + threadIdx.x;
    if (i < N) atomicAdd(&cnt[ntype[i]], 1);
}

__global__ void scan3_k(const int* __restrict__ cnt, int* __restrict__ off, int* __restrict__ cur) {
    if (threadIdx.x == 0) {
        off[0] = 0;
        off[1] = cnt[0];
        off[2] = cnt[0] + cnt[1];
        off[3] = cnt[0] + cnt[1] + cnt[2];
        cur[0] = 0; cur[1] = off[1]; cur[2] = off[2];
    }
}

__global__ void scatter_perm_k(const int* __restrict__ ntype, int N, int* __restrict__ cur,
                               int* __restrict__ perm) {
    int i = blockIdx.x * 256 + threadIdx.x;
    if (i < N) {
        int t = ntype[i];
        int p = atomicAdd(&cur[t], 1);
        perm[p] = i;
    }
}

// ---------------- typed GEMM (type-uniform blocks via perm buckets) ----------------
// out[perm[r]] = A[perm[r]] @ W[t]  (+ FINAL epilogue: alpha blend with x)
template<bool FINAL>
__global__ __launch_bounds__(256) void gemm_typed_k(
    const float* __restrict__ A, const float* __restrict__ W,
    float* __restrict__ out,
    const int* __restrict__ perm, const int* __restrict__ off,
    int N, int bpt,
    const float* __restrict__ denom, const float* __restrict__ x,
    const float* __restrict__ skip)
{
    __shared__ float As[BK][TM + 4];   // transposed, padded
    __shared__ float Bs[BK][TN];

    int t  = blockIdx.x / bpt;
    int bi = blockIdx.x % bpt;
    int i0 = off[t] + bi * TM;
    int iend = off[t + 1];
    if (i0 >= iend) return;

    int tid  = threadIdx.x;
    int col0 = blockIdx.y * TN;

    // staging assignment: each thread loads one float4 of A per k-tile
    int srow = tid >> 2;            // 0..63
    int sc4  = (tid & 3) * 4;       // 0,4,8,12
    int gsrow = (i0 + srow < iend) ? perm[i0 + srow] : -1;

    // micro-tile: 4 rows x 4 cols
    int tr = tid >> 4;              // 0..15
    int tc = tid & 15;              // 0..15
    int prow[4];
#pragma unroll
    for (int i = 0; i < 4; i++) {
        int idx = i0 + tr * 4 + i;
        prow[i] = (idx < iend) ? perm[idx] : -1;
    }

    float acc[4][4] = {};
    const float* Wt = W + (size_t)t * CDIM * CDIM;

    for (int k0 = 0; k0 < CDIM; k0 += BK) {
        float4 av = make_float4(0.f, 0.f, 0.f, 0.f);
        if (gsrow >= 0) {
            av = *(const float4*)(A + (size_t)gsrow * CDIM + k0 + sc4);
            if (FINAL) {
                float dn = denom[gsrow * HD + ((k0 + sc4) >> 5)];
                float s = dn > 0.f ? 1.0f / dn : 0.f;
                av.x *= s; av.y *= s; av.z *= s; av.w *= s;
            }
        }
        float4 bv = *(const float4*)(Wt + (size_t)(k0 + (tid >> 4)) * CDIM + col0 + (tid & 15) * 4);

        __syncthreads();   // previous iteration's LDS reads done
        As[sc4 + 0][srow] = av.x;
        As[sc4 + 1][srow] = av.y;
        As[sc4 + 2][srow] = av.z;
        As[sc4 + 3][srow] = av.w;
        *(float4*)&Bs[tid >> 4][(tid & 15) * 4] = bv;
        __syncthreads();

#pragma unroll
        for (int kk = 0; kk < BK; kk++) {
            float4 a = *(const float4*)&As[kk][tr * 4];
            float4 b = *(const float4*)&Bs[kk][tc * 4];
            acc[0][0] += a.x * b.x; acc[0][1] += a.x * b.y; acc[0][2] += a.x * b.z; acc[0][3] += a.x * b.w;
            acc[1][0] += a.y * b.x; acc[1][1] += a.y * b.y; acc[1][2] += a.y * b.z; acc[1][3] += a.y * b.w;
            acc[2][0] += a.z * b.x; acc[2][1] += a.z * b.y; acc[2][2] += a.z * b.z; acc[2][3] += a.z * b.w;
            acc[3][0] += a.w * b.x; acc[3][1] += a.w * b.y; acc[3][2] += a.w * b.z; acc[3][3] += a.w * b.w;
        }
    }

    float alpha = 0.f, beta = 0.f;
    if (FINAL) {
        alpha = 1.f / (1.f + __expf(-skip[t]));
        beta = 1.f - alpha;
    }

#pragma unroll
    for (int i = 0; i < 4; i++) {
        int row = prow[i];
        if (row < 0) continue;
        size_t base = (size_t)row * CDIM + col0 + tc * 4;
        float4 r = make_float4(acc[i][0], acc[i][1], acc[i][2], acc[i][3]);
        if (FINAL) {
            float4 xv = *(const float4*)(x + base);
            r.x = r.x * alpha + xv.x * beta;
            r.y = r.y * alpha + xv.y * beta;
            r.z = r.z * alpha + xv.z * beta;
            r.w = r.w * alpha + xv.w * beta;
        }
        *(float4*)(out + base) = r;
    }
}

// ---------------- edge kernel ----------------
// Per edge e, head h:
//   kw = k[src] @ Ratt[et,h];  logit = dot(kw, q[dst]) * pri[et,h] / sqrt(D);  ex = exp(logit)
//   mv = v[src] @ Rmsg[et,h];  acc[dst,h,:] += mv*ex;  denom[dst,h] += ex
// (softmax-max subtraction dropped: logits ~ N(0,1), exp is safe in fp32;
//  result is mathematically identical since numerator/denominator scale together)
#define EB 64
__global__ __launch_bounds__(256) void edge_k(
    const float* __restrict__ kbuf, const float* __restrict__ qbuf, const float* __restrict__ vbuf,
    const float* __restrict__ Ratt, const float* __restrict__ Rmsg, const float* __restrict__ pri,
    const int* __restrict__ src, const int* __restrict__ dst, const int* __restrict__ etype,
    float* __restrict__ acc, float* __restrict__ denom, int E)
{
    __shared__ float Ra[5][DD][DD];   // 20 KB
    __shared__ float Rm[5][DD][DD];   // 20 KB

    int tid = threadIdx.x;
    int el = tid >> 2;        // local edge 0..63
    int qq = tid & 3;         // quarter: owns douts qq*8 .. qq*8+7
    int e = blockIdx.x * EB + el;
    bool valid = e < E;
    int s = 0, d_ = 0, et = 0;
    if (valid) { s = src[e]; d_ = dst[e]; et = etype[e]; }

    const float rsD = 0.17677669529663687f;  // 1/sqrt(32)

    for (int h = 0; h < HD; ++h) {
        __syncthreads();
        // stage all 5 etypes' relation matrices for this head
#pragma unroll
        for (int t = 0; t < 5; ++t) {
            ((float4*)&Ra[t][0][0])[tid] = ((const float4*)(Ratt + ((size_t)(t * HD + h)) * (DD * DD)))[tid];
            ((float4*)&Rm[t][0][0])[tid] = ((const float4*)(Rmsg + ((size_t)(t * HD + h)) * (DD * DD)))[tid];
        }
        __syncthreads();
        if (!valid) continue;

        const float* kp = kbuf + (size_t)s  * CDIM + h * DD + qq * 8;
        const float* qp = qbuf + (size_t)d_ * CDIM + h * DD + qq * 8;
        const float* vp = vbuf + (size_t)s  * CDIM + h * DD + qq * 8;
        float4 k0 = *(const float4*)kp,  k1 = *(const float4*)(kp + 4);
        float4 q0 = *(const float4*)qp,  q1 = *(const float4*)(qp + 4);
        float4 v0 = *(const float4*)vp,  v1 = *(const float4*)(vp + 4);
        float kreg[8] = {k0.x, k0.y, k0.z, k0.w, k1.x, k1.y, k1.z, k1.w};
        float qreg[8] = {q0.x, q0.y, q0.z, q0.w, q1.x, q1.y, q1.z, q1.w};
        float vreg[8] = {v0.x, v0.y, v0.z, v0.w, v1.x, v1.y, v1.z, v1.w};

        float kw[8] = {};
        float mv[8] = {};
#pragma unroll
        for (int dd = 0; dd < DD; ++dd) {
            float kd = __shfl(kreg[dd & 7], dd >> 3, 4);
            float vd = __shfl(vreg[dd & 7], dd >> 3, 4);
            const float* rr = &Ra[et][dd][qq * 8];
            const float* rm = &Rm[et][dd][qq * 8];
#pragma unroll
            for (int j = 0; j < 8; ++j) {
                kw[j] += kd * rr[j];
                mv[j] += vd * rm[j];
            }
        }
        float adot = 0.f;
#pragma unroll
        for (int j = 0; j < 8; ++j) adot += kw[j] * qreg[j];
        adot += __shfl_xor(adot, 1, 4);
        adot += __shfl_xor(adot, 2, 4);
        float ex = __expf(adot * pri[et * HD + h] * rsD);

        float* ap = acc + (size_t)d_ * CDIM + h * DD + qq * 8;
#pragma unroll
        for (int j = 0; j < 8; ++j) atomicAdd(ap + j, mv[j] * ex);
        if (qq == 0) atomicAdd(denom + (size_t)d_ * HD + h, ex);
    }
}

// ---------------- launch ----------------
extern "C" void kernel_launch(void* const* d_in, const int* in_sizes, int n_in,
                              void* d_out, int out_size, void* d_ws, size_t ws_size,
                              hipStream_t stream) {
    const float* x    = (const float*)d_in[0];
    const float* Wk   = (const float*)d_in[1];
    const float* Wq   = (const float*)d_in[2];
    const float* Wv   = (const float*)d_in[3];
    const float* Ratt = (const float*)d_in[4];
    const float* Rmsg = (const float*)d_in[5];
    const float* pri  = (const float*)d_in[6];
    const float* Wa   = (const float*)d_in[7];
    const float* skip = (const float*)d_in[8];
    const int* src   = (const int*)d_in[9];
    const int* dst   = (const int*)d_in[10];
    const int* etype = (const int*)d_in[11];
    const int* ntype = (const int*)d_in[12];

    int N = in_sizes[12];
    int E = in_sizes[9];
    const size_t NC = (size_t)N * CDIM;

    float* ws   = (float*)d_ws;
    float* kb   = ws;
    float* qb   = kb + NC;
    float* vb   = qb + NC;
    float* accb = vb + NC;
    float* denb = accb + NC;           // N*H
    int* cnt  = (int*)(denb + (size_t)N * HD);
    int* off  = cnt + 4;
    int* cur  = off + 4;
    int* perm = cur + 4;

    // zero acc, denom, cnt/off/cur in one contiguous memset
    hipMemsetAsync(accb, 0, (NC + (size_t)N * HD) * sizeof(float) + 48, stream);

    count_ntype_k<<<(N + 255) / 256, 256, 0, stream>>>(ntype, N, cnt);
    scan3_k<<<1, 64, 0, stream>>>(cnt, off, cur);
    scatter_perm_k<<<(N + 255) / 256, 256, 0, stream>>>(ntype, N, cur, perm);

    int bpt = (N + TM - 1) / TM;
    dim3 gg(3 * bpt, CDIM / TN);
    gemm_typed_k<false><<<gg, 256, 0, stream>>>(x, Wk, kb, perm, off, N, bpt, nullptr, nullptr, nullptr);
    gemm_typed_k<false><<<gg, 256, 0, stream>>>(x, Wq, qb, perm, off, N, bpt, nullptr, nullptr, nullptr);
    gemm_typed_k<false><<<gg, 256, 0, stream>>>(x, Wv, vb, perm, off, N, bpt, nullptr, nullptr, nullptr);

    edge_k<<<(E + EB - 1) / EB, 256, 0, stream>>>(kb, qb, vb, Ratt, Rmsg, pri, src, dst, etype,
                                                  accb, denb, E);

    gemm_typed_k<true><<<gg, 256, 0, stream>>>(accb, Wa, (float*)d_out, perm, off, N, bpt,
                                               denb, x, skip);
}